// Round 10
// baseline (249.469 us; speedup 1.0000x reference)
//
#include <hip/hip_runtime.h>
#include <math.h>

#define NG   16
#define HID  256
#define TPTS 2048                    // table intervals; TPTS+1 entries in d_ws
#define GRID3 2048                   // token_sweep blocks (8192 waves)

typedef float f32x4 __attribute__((ext_vector_type(4)));

constexpr size_t BT      = 32ull * 2048ull;            // 65536 rows
constexpr size_t TOK_OFF = BT * HID;
constexpr size_t WT_OFF  = TOK_OFF + BT * NG * HID;
constexpr size_t NCHUNK  = BT * NG;                    // 1,048,576 1KB chunks
constexpr float  ZLO = -10.0f, ZHI = 10.0f;
constexpr float  ZSTEP  = (ZHI - ZLO) / TPTS;
constexpr float  ZSCALE = TPTS / (ZHI - ZLO);

__device__ __forceinline__ float rln(float v, int l) {  // const-lane -> SGPR
    return __int_as_float(__builtin_amdgcn_readlane(__float_as_int(v), l));
}

// ---- kernel 1: tabulate F(z) = sum_h tanh(z*w_gp[h]+b_gp[h])*w_sp[h] + b_sp
__global__ __launch_bounds__(256) void build_table(
    const float* __restrict__ w_gp, const float* __restrict__ b_gp,
    const float* __restrict__ w_sp, const float* __restrict__ b_sp,
    float* __restrict__ tbl)
{
    const int i = blockIdx.x;              // 0..TPTS
    const int h = threadIdx.x;
    const float z = ZLO + (float)i * ZSTEP;
    float v = tanhf(fmaf(z, w_gp[h], b_gp[h])) * w_sp[h];
    v += __shfl_xor(v, 1, 64);
    v += __shfl_xor(v, 2, 64);
    v += __shfl_xor(v, 4, 64);
    v += __shfl_xor(v, 8, 64);
    v += __shfl_xor(v, 16, 64);
    v += __shfl_xor(v, 32, 64);
    __shared__ float sred[4];
    if ((h & 63) == 0) sred[h >> 6] = v;
    __syncthreads();
    if (h == 0) tbl[i] = sred[0] + sred[1] + sred[2] + sred[3] + b_sp[0];
}

// ---- kernel 2: gv + scores + softmax + visit + weights (~95 MB traffic) ----
// wave = 4 rows; lane = (row j = lane>>4, group g = lane&15)
__global__ __launch_bounds__(256) void compute_kernel(
    const float*  __restrict__ x,      // (BT,64)
    const f32x4*  __restrict__ w_gp4,  // (64) float4
    const f32x4*  __restrict__ b_gp4,
    const float*  __restrict__ tbl,    // (TPTS+1)
    float* __restrict__ gvbuf,         // (BT*NG) out: group means
    float* __restrict__ out)
{
    const int lane = threadIdx.x & 63;
    const int wv   = threadIdx.x >> 6;
    const size_t row0 = ((size_t)blockIdx.x * 4 + wv) * 4;  // 4 rows per wave

    __shared__ float sx[4][4][68];     // per-wave staging (+pad, 16B-aligned)
    {
        const f32x4 xl = ((const f32x4*)x)[row0 * 16 + lane];
        const int r = lane >> 4, c = lane & 15;
        *(f32x4*)&sx[wv][r][c * 4] = xl;       // intra-wave only: no barrier
    }

    const int j   = lane >> 4;         // row within wave
    const int g   = lane & 15;         // group
    const int sub = g & 3;             // segment sizes [1,3,5,7] tiled x4
    const int sz  = 2 * sub + 1;
    const int beg = ((g >> 2) << 4) + sub * sub;   // {0,1,4,9}+16*chunk

    float s = 0.0f;
    #pragma unroll
    for (int i = 0; i < 7; ++i)
        if (i < sz) s += sx[wv][j][beg + i];
    const float gv = s * __builtin_amdgcn_rcpf((float)sz);

    // gv out (plain store; reaches L3 at kernel-end release for the sweep)
    gvbuf[row0 * NG + lane] = gv;

    // ---- score via table lookup + lerp ----
    float idxf = fminf(fmaxf((gv - ZLO) * ZSCALE, 0.0f), (float)TPTS - 0.001f);
    const int   i0 = (int)idxf;
    const float fr = idxf - (float)i0;
    const float t0 = tbl[i0], t1 = tbl[i0 + 1];
    const float score = fmaf(fr, t1 - t0, t0);

    // ---- softmax across the 16-lane group ----
    float m = score;
    m = fmaxf(m, __shfl_xor(m, 1, 64));
    m = fmaxf(m, __shfl_xor(m, 2, 64));
    m = fmaxf(m, __shfl_xor(m, 4, 64));
    m = fmaxf(m, __shfl_xor(m, 8, 64));
    const float e = __expf(score - m);
    float ssum = e;
    ssum += __shfl_xor(ssum, 1, 64);
    ssum += __shfl_xor(ssum, 2, 64);
    ssum += __shfl_xor(ssum, 4, 64);
    ssum += __shfl_xor(ssum, 8, 64);
    const float w = e / ssum;          // weight for (row j, group g)

    __builtin_nontemporal_store(w, out + WT_OFF + row0 * NG + lane);

    // ---- dot_j = sum_g wt_g*gv_g ; visit = dot*w_gp + b_gp (exact) ----
    float d = w * gv;
    d += __shfl_xor(d, 1, 64);
    d += __shfl_xor(d, 2, 64);
    d += __shfl_xor(d, 4, 64);
    d += __shfl_xor(d, 8, 64);

    const f32x4 wg = w_gp4[lane];
    const f32x4 bg = b_gp4[lane];
    #pragma unroll
    for (int jj = 0; jj < 4; ++jj) {
        const float dj = rln(d, jj * 16);
        f32x4 vis;
        vis.x = fmaf(dj, wg.x, bg.x);
        vis.y = fmaf(dj, wg.y, bg.y);
        vis.z = fmaf(dj, wg.z, bg.z);
        vis.w = fmaf(dj, wg.w, bg.w);
        __builtin_nontemporal_store(vis,
            (f32x4*)(out + (row0 + jj) * HID + 4 * lane));
    }
}

// ---- kernel 3: fill-shaped token sweep. Grid-stride, wave-chunk = one
// (row,g) 1 KB store; consecutive waves -> consecutive addresses -> dense
// device-wide front. PLAIN stores (L2 write-aggregation, like the runtime
// fill) + 2-way chunk ILP with double prefetch. Exactly 128 iters/wave.
__global__ __launch_bounds__(256) void token_sweep(
    const float*  __restrict__ gvbuf,  // (BT*NG)
    const f32x4*  __restrict__ w_gp4,
    const f32x4*  __restrict__ b_gp4,
    float* __restrict__ out)
{
    const int lane = threadIdx.x & 63;
    const int wv   = threadIdx.x >> 6;
    const f32x4 wg = w_gp4[lane];
    const f32x4 bg = b_gp4[lane];
    constexpr size_t NW    = (size_t)GRID3 * 4;          // 8192 waves
    constexpr int    NITER = (int)(NCHUNK / NW);         // 128 (exact)

    size_t c = (size_t)blockIdx.x * 4 + wv;
    float* __restrict__ tok = out + TOK_OFF + 4 * lane;

    float gv0 = gvbuf[c];              // broadcast loads, L3-resident
    float gv1 = gvbuf[c + NW];
    #pragma unroll 1
    for (int it = 0; it < NITER; it += 2) {
        float n0 = 0.0f, n1 = 0.0f;
        if (it + 2 < NITER) {          // issue next pair's loads early
            n0 = gvbuf[c + 2 * NW];
            n1 = gvbuf[c + 3 * NW];
        }
        f32x4 t0, t1;
        t0.x = fmaf(gv0, wg.x, bg.x);
        t0.y = fmaf(gv0, wg.y, bg.y);
        t0.z = fmaf(gv0, wg.z, bg.z);
        t0.w = fmaf(gv0, wg.w, bg.w);
        *(f32x4*)(tok + c * HID) = t0;             // plain store: L2-aggregated
        t1.x = fmaf(gv1, wg.x, bg.x);
        t1.y = fmaf(gv1, wg.y, bg.y);
        t1.z = fmaf(gv1, wg.z, bg.z);
        t1.w = fmaf(gv1, wg.w, bg.w);
        *(f32x4*)(tok + (c + NW) * HID) = t1;
        gv0 = n0;
        gv1 = n1;
        c += 2 * NW;
    }
}

extern "C" void kernel_launch(void* const* d_in, const int* in_sizes, int n_in,
                              void* d_out, int out_size, void* d_ws, size_t ws_size,
                              hipStream_t stream) {
    (void)in_sizes; (void)n_in; (void)out_size; (void)ws_size;
    const float* x    = (const float*)d_in[0];
    const float* w_gp = (const float*)d_in[1];
    const float* b_gp = (const float*)d_in[2];
    const float* w_sp = (const float*)d_in[3];
    const float* b_sp = (const float*)d_in[4];
    float* out = (float*)d_out;
    float* tbl   = (float*)d_ws;                          // 8196 B
    float* gvbuf = (float*)((char*)d_ws + 16384);         // 4 MB; needs ws>=4.3MB

    build_table<<<dim3(TPTS + 1), dim3(256), 0, stream>>>(
        w_gp, b_gp, w_sp, b_sp, tbl);

    compute_kernel<<<dim3((unsigned)(BT / 16)), dim3(256), 0, stream>>>(
        x, (const f32x4*)w_gp, (const f32x4*)b_gp, tbl, gvbuf, out);

    token_sweep<<<dim3(GRID3), dim3(256), 0, stream>>>(
        gvbuf, (const f32x4*)w_gp, (const f32x4*)b_gp, out);
}

// Round 11
// 241.899 us; speedup vs baseline: 1.0313x; 1.0313x over previous
//
#include <hip/hip_runtime.h>
#include <math.h>

#define NG   16
#define HID  256
#define TPTS 2048                    // table intervals; TPTS+1 entries in d_ws
#define GRID3 2048                   // token_sweep blocks (8192 waves)

typedef float f32x4 __attribute__((ext_vector_type(4)));

constexpr size_t BT      = 32ull * 2048ull;            // 65536 rows
constexpr size_t TOK_OFF = BT * HID;
constexpr size_t WT_OFF  = TOK_OFF + BT * NG * HID;
constexpr size_t NCHUNK  = BT * NG;                    // 1,048,576 1KB chunks
constexpr float  ZLO = -10.0f, ZHI = 10.0f;
constexpr float  ZSTEP  = (ZHI - ZLO) / TPTS;
constexpr float  ZSCALE = TPTS / (ZHI - ZLO);

__device__ __forceinline__ float rln(float v, int l) {  // const-lane -> SGPR
    return __int_as_float(__builtin_amdgcn_readlane(__float_as_int(v), l));
}

// ---- kernel 1: tabulate F(z) = sum_h tanh(z*w_gp[h]+b_gp[h])*w_sp[h] + b_sp
__global__ __launch_bounds__(256) void build_table(
    const float* __restrict__ w_gp, const float* __restrict__ b_gp,
    const float* __restrict__ w_sp, const float* __restrict__ b_sp,
    float* __restrict__ tbl)
{
    const int i = blockIdx.x;              // 0..TPTS
    const int h = threadIdx.x;
    const float z = ZLO + (float)i * ZSTEP;
    float v = tanhf(fmaf(z, w_gp[h], b_gp[h])) * w_sp[h];
    v += __shfl_xor(v, 1, 64);
    v += __shfl_xor(v, 2, 64);
    v += __shfl_xor(v, 4, 64);
    v += __shfl_xor(v, 8, 64);
    v += __shfl_xor(v, 16, 64);
    v += __shfl_xor(v, 32, 64);
    __shared__ float sred[4];
    if ((h & 63) == 0) sred[h >> 6] = v;
    __syncthreads();
    if (h == 0) tbl[i] = sred[0] + sred[1] + sred[2] + sred[3] + b_sp[0];
}

// ---- kernel 2: gv + scores + softmax + visit + weights (~95 MB traffic) ----
// wave = 4 rows; lane = (row j = lane>>4, group g = lane&15)
__global__ __launch_bounds__(256) void compute_kernel(
    const float*  __restrict__ x,      // (BT,64)
    const f32x4*  __restrict__ w_gp4,  // (64) float4
    const f32x4*  __restrict__ b_gp4,
    const float*  __restrict__ tbl,    // (TPTS+1)
    float* __restrict__ gvbuf,         // (BT*NG) out: group means
    float* __restrict__ out)
{
    const int lane = threadIdx.x & 63;
    const int wv   = threadIdx.x >> 6;
    const size_t row0 = ((size_t)blockIdx.x * 4 + wv) * 4;  // 4 rows per wave

    __shared__ float sx[4][4][68];     // per-wave staging (+pad, 16B-aligned)
    {
        const f32x4 xl = ((const f32x4*)x)[row0 * 16 + lane];
        const int r = lane >> 4, c = lane & 15;
        *(f32x4*)&sx[wv][r][c * 4] = xl;       // intra-wave only: no barrier
    }

    const int j   = lane >> 4;         // row within wave
    const int g   = lane & 15;         // group
    const int sub = g & 3;             // segment sizes [1,3,5,7] tiled x4
    const int sz  = 2 * sub + 1;
    const int beg = ((g >> 2) << 4) + sub * sub;   // {0,1,4,9}+16*chunk

    float s = 0.0f;
    #pragma unroll
    for (int i = 0; i < 7; ++i)
        if (i < sz) s += sx[wv][j][beg + i];
    const float gv = s * __builtin_amdgcn_rcpf((float)sz);

    // gv out (plain store; stays L2/L3-resident for the sweep's re-read)
    gvbuf[row0 * NG + lane] = gv;

    // ---- score via table lookup + lerp ----
    float idxf = fminf(fmaxf((gv - ZLO) * ZSCALE, 0.0f), (float)TPTS - 0.001f);
    const int   i0 = (int)idxf;
    const float fr = idxf - (float)i0;
    const float t0 = tbl[i0], t1 = tbl[i0 + 1];
    const float score = fmaf(fr, t1 - t0, t0);

    // ---- softmax across the 16-lane group ----
    float m = score;
    m = fmaxf(m, __shfl_xor(m, 1, 64));
    m = fmaxf(m, __shfl_xor(m, 2, 64));
    m = fmaxf(m, __shfl_xor(m, 4, 64));
    m = fmaxf(m, __shfl_xor(m, 8, 64));
    const float e = __expf(score - m);
    float ssum = e;
    ssum += __shfl_xor(ssum, 1, 64);
    ssum += __shfl_xor(ssum, 2, 64);
    ssum += __shfl_xor(ssum, 4, 64);
    ssum += __shfl_xor(ssum, 8, 64);
    const float w = e / ssum;          // weight for (row j, group g)

    __builtin_nontemporal_store(w, out + WT_OFF + row0 * NG + lane);

    // ---- dot_j = sum_g wt_g*gv_g ; visit = dot*w_gp + b_gp (exact) ----
    float d = w * gv;
    d += __shfl_xor(d, 1, 64);
    d += __shfl_xor(d, 2, 64);
    d += __shfl_xor(d, 4, 64);
    d += __shfl_xor(d, 8, 64);

    const f32x4 wg = w_gp4[lane];
    const f32x4 bg = b_gp4[lane];
    #pragma unroll
    for (int jj = 0; jj < 4; ++jj) {
        const float dj = rln(d, jj * 16);
        f32x4 vis;
        vis.x = fmaf(dj, wg.x, bg.x);
        vis.y = fmaf(dj, wg.y, bg.y);
        vis.z = fmaf(dj, wg.z, bg.z);
        vis.w = fmaf(dj, wg.w, bg.w);
        __builtin_nontemporal_store(vis,
            (f32x4*)(out + (row0 + jj) * HID + 4 * lane));
    }
}

// ---- kernel 3: fill-shaped token sweep. Grid-stride, wave-chunk = one
// (row,g) 1 KB NT store; consecutive waves -> consecutive addresses ->
// dense device-wide front. NT is load-bearing (R10: plain stores -18%).
// 2-way chunk ILP + double prefetch. Exactly 128 iters/wave.
__global__ __launch_bounds__(256) void token_sweep(
    const float*  __restrict__ gvbuf,  // (BT*NG)
    const f32x4*  __restrict__ w_gp4,
    const f32x4*  __restrict__ b_gp4,
    float* __restrict__ out)
{
    const int lane = threadIdx.x & 63;
    const int wv   = threadIdx.x >> 6;
    const f32x4 wg = w_gp4[lane];
    const f32x4 bg = b_gp4[lane];
    constexpr size_t NW    = (size_t)GRID3 * 4;          // 8192 waves
    constexpr int    NITER = (int)(NCHUNK / NW);         // 128 (exact)

    size_t c = (size_t)blockIdx.x * 4 + wv;
    float* __restrict__ tok = out + TOK_OFF + 4 * lane;

    float gv0 = gvbuf[c];              // broadcast loads, L2/L3-resident
    float gv1 = gvbuf[c + NW];
    #pragma unroll 1
    for (int it = 0; it < NITER; it += 2) {
        float n0 = 0.0f, n1 = 0.0f;
        if (it + 2 < NITER) {          // issue next pair's loads early
            n0 = gvbuf[c + 2 * NW];
            n1 = gvbuf[c + 3 * NW];
        }
        f32x4 t0, t1;
        t0.x = fmaf(gv0, wg.x, bg.x);
        t0.y = fmaf(gv0, wg.y, bg.y);
        t0.z = fmaf(gv0, wg.z, bg.z);
        t0.w = fmaf(gv0, wg.w, bg.w);
        __builtin_nontemporal_store(t0, (f32x4*)(tok + c * HID));
        t1.x = fmaf(gv1, wg.x, bg.x);
        t1.y = fmaf(gv1, wg.y, bg.y);
        t1.z = fmaf(gv1, wg.z, bg.z);
        t1.w = fmaf(gv1, wg.w, bg.w);
        __builtin_nontemporal_store(t1, (f32x4*)(tok + (c + NW) * HID));
        gv0 = n0;
        gv1 = n1;
        c += 2 * NW;
    }
}

extern "C" void kernel_launch(void* const* d_in, const int* in_sizes, int n_in,
                              void* d_out, int out_size, void* d_ws, size_t ws_size,
                              hipStream_t stream) {
    (void)in_sizes; (void)n_in; (void)out_size; (void)ws_size;
    const float* x    = (const float*)d_in[0];
    const float* w_gp = (const float*)d_in[1];
    const float* b_gp = (const float*)d_in[2];
    const float* w_sp = (const float*)d_in[3];
    const float* b_sp = (const float*)d_in[4];
    float* out = (float*)d_out;
    float* tbl   = (float*)d_ws;                          // 8196 B
    float* gvbuf = (float*)((char*)d_ws + 16384);         // 4 MB; needs ws>=4.3MB

    build_table<<<dim3(TPTS + 1), dim3(256), 0, stream>>>(
        w_gp, b_gp, w_sp, b_sp, tbl);

    compute_kernel<<<dim3((unsigned)(BT / 16)), dim3(256), 0, stream>>>(
        x, (const f32x4*)w_gp, (const f32x4*)b_gp, tbl, gvbuf, out);

    token_sweep<<<dim3(GRID3), dim3(256), 0, stream>>>(
        gvbuf, (const f32x4*)w_gp, (const f32x4*)b_gp, out);
}

// Round 12
// 218.234 us; speedup vs baseline: 1.1431x; 1.1084x over previous
//
#include <hip/hip_runtime.h>
#include <math.h>

#define NG   16
#define HID  256
#define TPTS 2048                    // table intervals; TPTS+1 entries in d_ws
#define GRID3 2048                   // sweep blocks (8192 waves)

typedef float f32x4 __attribute__((ext_vector_type(4)));

constexpr size_t BT       = 32ull * 2048ull;           // 65536 rows
constexpr size_t TOK_OFF  = BT * HID;
constexpr size_t WT_OFF   = TOK_OFF + BT * NG * HID;
constexpr size_t NCHUNK_T = BT * NG;                   // token 1KB chunks
constexpr size_t NCHUNK_U = BT * (NG + 1);             // visit+token chunks
constexpr float  ZLO = -10.0f, ZHI = 10.0f;
constexpr float  ZSTEP  = (ZHI - ZLO) / TPTS;
constexpr float  ZSCALE = TPTS / (ZHI - ZLO);

__device__ __forceinline__ float rln(float v, int l) {  // const-lane -> SGPR
    return __int_as_float(__builtin_amdgcn_readlane(__float_as_int(v), l));
}

// ---- kernel 1: tabulate F(z) = sum_h tanh(z*w_gp[h]+b_gp[h])*w_sp[h] + b_sp
__global__ __launch_bounds__(256) void build_table(
    const float* __restrict__ w_gp, const float* __restrict__ b_gp,
    const float* __restrict__ w_sp, const float* __restrict__ b_sp,
    float* __restrict__ tbl)
{
    const int i = blockIdx.x;              // 0..TPTS
    const int h = threadIdx.x;
    const float z = ZLO + (float)i * ZSTEP;
    float v = tanhf(fmaf(z, w_gp[h], b_gp[h])) * w_sp[h];
    v += __shfl_xor(v, 1, 64);
    v += __shfl_xor(v, 2, 64);
    v += __shfl_xor(v, 4, 64);
    v += __shfl_xor(v, 8, 64);
    v += __shfl_xor(v, 16, 64);
    v += __shfl_xor(v, 32, 64);
    __shared__ float sred[4];
    if ((h & 63) == 0) sred[h >> 6] = v;
    __syncthreads();
    if (h == 0) tbl[i] = sred[0] + sred[1] + sred[2] + sred[3] + b_sp[0];
}

// ---- shared compute body: gv, score, softmax; returns w and gv ----
// wave = 4 rows; lane = (row j = lane>>4, group g = lane&15)
template <bool UNIFIED>
__global__ __launch_bounds__(256) void compute_kernel(
    const float*  __restrict__ x,      // (BT,64)
    const f32x4*  __restrict__ w_gp4,  // (64) float4
    const f32x4*  __restrict__ b_gp4,
    const float*  __restrict__ tbl,    // (TPTS+1)
    float* __restrict__ vbuf,          // UNIFIED: (BT*(NG+1)); else gv (BT*NG)
    float* __restrict__ out)
{
    const int lane = threadIdx.x & 63;
    const int wv   = threadIdx.x >> 6;
    const size_t row0 = ((size_t)blockIdx.x * 4 + wv) * 4;  // 4 rows per wave

    __shared__ float sx[4][4][68];     // per-wave staging (+pad, 16B-aligned)
    {
        const f32x4 xl = ((const f32x4*)x)[row0 * 16 + lane];
        const int r = lane >> 4, c = lane & 15;
        *(f32x4*)&sx[wv][r][c * 4] = xl;       // intra-wave only: no barrier
    }

    const int j   = lane >> 4;         // row within wave
    const int g   = lane & 15;         // group
    const int sub = g & 3;             // segment sizes [1,3,5,7] tiled x4
    const int sz  = 2 * sub + 1;
    const int beg = ((g >> 2) << 4) + sub * sub;   // {0,1,4,9}+16*chunk

    float s = 0.0f;
    #pragma unroll
    for (int i = 0; i < 7; ++i)
        if (i < sz) s += sx[wv][j][beg + i];
    const float gv = s * __builtin_amdgcn_rcpf((float)sz);

    // publish gv for the sweep
    if (UNIFIED) vbuf[BT + row0 * NG + lane] = gv;
    else         vbuf[row0 * NG + lane] = gv;

    // ---- score via table lookup + lerp ----
    float idxf = fminf(fmaxf((gv - ZLO) * ZSCALE, 0.0f), (float)TPTS - 0.001f);
    const int   i0 = (int)idxf;
    const float fr = idxf - (float)i0;
    const float t0 = tbl[i0], t1 = tbl[i0 + 1];
    const float score = fmaf(fr, t1 - t0, t0);

    // ---- softmax across the 16-lane group ----
    float m = score;
    m = fmaxf(m, __shfl_xor(m, 1, 64));
    m = fmaxf(m, __shfl_xor(m, 2, 64));
    m = fmaxf(m, __shfl_xor(m, 4, 64));
    m = fmaxf(m, __shfl_xor(m, 8, 64));
    const float e = __expf(score - m);
    float ssum = e;
    ssum += __shfl_xor(ssum, 1, 64);
    ssum += __shfl_xor(ssum, 2, 64);
    ssum += __shfl_xor(ssum, 4, 64);
    ssum += __shfl_xor(ssum, 8, 64);
    const float w = e / ssum;          // weight for (row j, group g)

    __builtin_nontemporal_store(w, out + WT_OFF + row0 * NG + lane);

    // ---- dot_j = sum_g wt_g*gv_g ----
    float d = w * gv;
    d += __shfl_xor(d, 1, 64);
    d += __shfl_xor(d, 2, 64);
    d += __shfl_xor(d, 4, 64);
    d += __shfl_xor(d, 8, 64);

    if (UNIFIED) {
        if (g == 0) vbuf[row0 + j] = d;        // dot -> visit chunk value
    } else {
        // write visit directly (R9 fallback path)
        const f32x4 wg = w_gp4[lane];
        const f32x4 bg = b_gp4[lane];
        #pragma unroll
        for (int jj = 0; jj < 4; ++jj) {
            const float dj = rln(d, jj * 16);
            f32x4 vis;
            vis.x = fmaf(dj, wg.x, bg.x);
            vis.y = fmaf(dj, wg.y, bg.y);
            vis.z = fmaf(dj, wg.z, bg.z);
            vis.w = fmaf(dj, wg.w, bg.w);
            __builtin_nontemporal_store(vis,
                (f32x4*)(out + (row0 + jj) * HID + 4 * lane));
        }
    }
}

// ---- kernel 3 (unified): branch-free fill-shaped sweep over visit+tokens.
// chunk c (1 KB) = out[c*256 .. c*256+255] = vbuf[c]*w_gp + b_gp.
// Grid-stride: consecutive waves -> consecutive addresses -> one dense
// device-wide front. NT stores (R10: plain -18%); single prefetch (R11:
// 2-way ILP -13%). Exactly 136 iters/wave.
__global__ __launch_bounds__(256) void sweep_unified(
    const float*  __restrict__ vbuf,   // (BT*(NG+1))
    const f32x4*  __restrict__ w_gp4,
    const f32x4*  __restrict__ b_gp4,
    float* __restrict__ out)
{
    const int lane = threadIdx.x & 63;
    const int wv   = threadIdx.x >> 6;
    const f32x4 wg = w_gp4[lane];
    const f32x4 bg = b_gp4[lane];
    constexpr size_t NW    = (size_t)GRID3 * 4;          // 8192 waves
    constexpr int    NITER = (int)(NCHUNK_U / NW);       // 136 (exact)

    size_t c = (size_t)blockIdx.x * 4 + wv;
    float* __restrict__ base = out + 4 * lane;

    float v = vbuf[c];                 // broadcast load, L2-resident
    #pragma unroll 1
    for (int it = 0; it < NITER; ++it) {
        float nxt = 0.0f;
        if (it + 1 < NITER) nxt = vbuf[c + NW];   // issue next load early
        f32x4 t;
        t.x = fmaf(v, wg.x, bg.x);
        t.y = fmaf(v, wg.y, bg.y);
        t.z = fmaf(v, wg.z, bg.z);
        t.w = fmaf(v, wg.w, bg.w);
        __builtin_nontemporal_store(t, (f32x4*)(base + c * HID));
        v = nxt;
        c += NW;
    }
}

// ---- kernel 3 (fallback = R9): token-only sweep ----
__global__ __launch_bounds__(256) void token_sweep(
    const float*  __restrict__ gvbuf,  // (BT*NG)
    const f32x4*  __restrict__ w_gp4,
    const f32x4*  __restrict__ b_gp4,
    float* __restrict__ out)
{
    const int lane = threadIdx.x & 63;
    const int wv   = threadIdx.x >> 6;
    const f32x4 wg = w_gp4[lane];
    const f32x4 bg = b_gp4[lane];
    constexpr size_t NW    = (size_t)GRID3 * 4;
    constexpr int    NITER = (int)(NCHUNK_T / NW);       // 128 (exact)

    size_t c = (size_t)blockIdx.x * 4 + wv;
    float* __restrict__ tok = out + TOK_OFF + 4 * lane;

    float v = gvbuf[c];
    #pragma unroll 1
    for (int it = 0; it < NITER; ++it) {
        float nxt = 0.0f;
        if (it + 1 < NITER) nxt = gvbuf[c + NW];
        f32x4 t;
        t.x = fmaf(v, wg.x, bg.x);
        t.y = fmaf(v, wg.y, bg.y);
        t.z = fmaf(v, wg.z, bg.z);
        t.w = fmaf(v, wg.w, bg.w);
        __builtin_nontemporal_store(t, (f32x4*)(tok + c * HID));
        v = nxt;
        c += NW;
    }
}

extern "C" void kernel_launch(void* const* d_in, const int* in_sizes, int n_in,
                              void* d_out, int out_size, void* d_ws, size_t ws_size,
                              hipStream_t stream) {
    (void)in_sizes; (void)n_in; (void)out_size;
    const float* x    = (const float*)d_in[0];
    const float* w_gp = (const float*)d_in[1];
    const float* b_gp = (const float*)d_in[2];
    const float* w_sp = (const float*)d_in[3];
    const float* b_sp = (const float*)d_in[4];
    float* out = (float*)d_out;
    float* tbl  = (float*)d_ws;                           // 8196 B
    float* vbuf = (float*)((char*)d_ws + 16384);          // 4.46 MB (unified)

    build_table<<<dim3(TPTS + 1), dim3(256), 0, stream>>>(
        w_gp, b_gp, w_sp, b_sp, tbl);

    const size_t need = 16384 + NCHUNK_U * sizeof(float); // ~4.47 MB
    if (ws_size >= need) {
        compute_kernel<true><<<dim3((unsigned)(BT / 16)), dim3(256), 0, stream>>>(
            x, (const f32x4*)w_gp, (const f32x4*)b_gp, tbl, vbuf, out);
        sweep_unified<<<dim3(GRID3), dim3(256), 0, stream>>>(
            vbuf, (const f32x4*)w_gp, (const f32x4*)b_gp, out);
    } else {
        compute_kernel<false><<<dim3((unsigned)(BT / 16)), dim3(256), 0, stream>>>(
            x, (const f32x4*)w_gp, (const f32x4*)b_gp, tbl, vbuf, out);
        token_sweep<<<dim3(GRID3), dim3(256), 0, stream>>>(
            vbuf, (const f32x4*)w_gp, (const f32x4*)b_gp, out);
    }
}